// Round 1
// baseline (353.761 us; speedup 1.0000x reference)
//
#include <hip/hip_runtime.h>
#include <hip/hip_bf16.h>

#define T_TOK 4096
#define DDIM  768
#define IDIM  2048
#define NEXP  8

typedef __attribute__((ext_vector_type(8))) short  bfrag;   // 8 bf16 = 4 VGPR
typedef __attribute__((ext_vector_type(4))) float  ffrag;   // 4 f32 acc

static __device__ __forceinline__ unsigned short f2bf(float f) {
    union { float f; unsigned u; } v; v.f = f;
    unsigned r = v.u + 0x7FFFu + ((v.u >> 16) & 1u);   // RNE
    return (unsigned short)(r >> 16);
}

// ws int layout: counts[8] @0, cursors[8] @8, offsets[9] @16
__global__ void k_hist(const int* __restrict__ pos, int* __restrict__ ws_i) {
    int t = blockIdx.x * blockDim.x + threadIdx.x;
    if (t < T_TOK) atomicAdd(&ws_i[pos[t]], 1);
}

__global__ void k_scan(int* __restrict__ ws_i) {
    if (threadIdx.x == 0) {
        int s = 0;
        for (int e = 0; e < NEXP; ++e) { ws_i[16 + e] = s; ws_i[8 + e] = s; s += ws_i[e]; }
        ws_i[16 + NEXP] = s;
    }
}

__global__ void k_perm(const int* __restrict__ pos, int* __restrict__ ws_i,
                       int* __restrict__ perm) {
    int t = blockIdx.x * blockDim.x + threadIdx.x;
    if (t < T_TOK) {
        int e = pos[t];
        int p = atomicAdd(&ws_i[8 + e], 1);
        perm[p] = t;
    }
}

// gather + fp32->bf16: one block per gathered row, 192 thr * float4 = 768
__global__ void k_gather(const float* __restrict__ x, const int* __restrict__ perm,
                         unsigned short* __restrict__ xg) {
    int p = blockIdx.x;
    int tok = perm[p];
    int j = threadIdx.x * 4;
    const float4 v = *reinterpret_cast<const float4*>(x + (size_t)tok * DDIM + j);
    uint2 o;
    o.x = f2bf(v.x) | ((unsigned)f2bf(v.y) << 16);
    o.y = f2bf(v.z) | ((unsigned)f2bf(v.w) << 16);
    *reinterpret_cast<uint2*>(xg + (size_t)p * DDIM + j) = o;
}

// GEMM1: [cnt x 768] (gathered bf16) x gate/up^T tile -> h = silu(g)*u, bf16
// tile: BM=128, BN=64 (per matrix), BK=32. 4 waves: wm=wave&1 (64 rows), wn=wave>>1 (32 cols)
__launch_bounds__(256, 2)
__global__ void k_gemm1(const unsigned short* __restrict__ xg,
                        const float* __restrict__ gate_w,
                        const float* __restrict__ up_w,
                        unsigned short* __restrict__ hg,
                        const int* __restrict__ ws_i) {
    const int e   = blockIdx.z;
    const int cnt = ws_i[e];
    const int m0  = blockIdx.y * 128;
    if (m0 >= cnt) return;
    const int off = ws_i[16 + e];
    const int n0  = blockIdx.x * 64;

    const int tid  = threadIdx.x;
    const int lane = tid & 63;
    const int wave = tid >> 6;
    const int wm   = wave & 1;
    const int wn   = wave >> 1;

    // row stride 56 bf16 = 112 B: 16B-aligned, bank-uniform
    __shared__ __align__(16) unsigned short lsA[128 * 56];
    __shared__ __align__(16) unsigned short lsG[64 * 56];
    __shared__ __align__(16) unsigned short lsU[64 * 56];

    const float* gate_e = gate_w + (size_t)e * IDIM * DDIM;
    const float* up_e   = up_w   + (size_t)e * IDIM * DDIM;

    ffrag accG[4][2], accU[4][2];
    const ffrag fz = {0.f, 0.f, 0.f, 0.f};
    for (int mi = 0; mi < 4; ++mi)
        for (int ni = 0; ni < 2; ++ni) { accG[mi][ni] = fz; accU[mi][ni] = fz; }

    for (int kt = 0; kt < DDIM / 32; ++kt) {
        const int k0 = kt * 32;
        // stage A: 128 rows x 32 bf16 = 512 x 16B chunks, 2/thread
        #pragma unroll
        for (int i = 0; i < 2; ++i) {
            int c = tid + i * 256;
            int row = c >> 2, q = c & 3;
            int grow = off + m0 + row; if (grow > T_TOK - 1) grow = T_TOK - 1;
            const uint4 v = *reinterpret_cast<const uint4*>(xg + (size_t)grow * DDIM + k0 + q * 8);
            *reinterpret_cast<uint4*>(&lsA[row * 56 + q * 8]) = v;
        }
        // stage B gate+up: 2 x (64 rows x 32 f32) = 1024 float4, 4/thread, cvt to bf16
        #pragma unroll
        for (int i = 0; i < 4; ++i) {
            int f   = tid + i * 256;
            int mat = f >> 9;
            int c   = f & 511;
            int row = c >> 3, q = c & 7;
            const float* src = mat ? up_e : gate_e;
            const float4 v = *reinterpret_cast<const float4*>(src + (size_t)(n0 + row) * DDIM + k0 + q * 4);
            uint2 o;
            o.x = f2bf(v.x) | ((unsigned)f2bf(v.y) << 16);
            o.y = f2bf(v.z) | ((unsigned)f2bf(v.w) << 16);
            unsigned short* dst = mat ? lsU : lsG;
            *reinterpret_cast<uint2*>(&dst[row * 56 + q * 4]) = o;
        }
        __syncthreads();

        const int koff = (lane >> 4) * 8;
        const int rsel = lane & 15;
        bfrag a[4], bg[2], bu[2];
        #pragma unroll
        for (int mi = 0; mi < 4; ++mi)
            a[mi] = *reinterpret_cast<const bfrag*>(&lsA[(wm * 64 + mi * 16 + rsel) * 56 + koff]);
        #pragma unroll
        for (int ni = 0; ni < 2; ++ni) {
            bg[ni] = *reinterpret_cast<const bfrag*>(&lsG[(wn * 32 + ni * 16 + rsel) * 56 + koff]);
            bu[ni] = *reinterpret_cast<const bfrag*>(&lsU[(wn * 32 + ni * 16 + rsel) * 56 + koff]);
        }
        #pragma unroll
        for (int mi = 0; mi < 4; ++mi)
            #pragma unroll
            for (int ni = 0; ni < 2; ++ni) {
                accG[mi][ni] = __builtin_amdgcn_mfma_f32_16x16x32_bf16(a[mi], bg[ni], accG[mi][ni], 0, 0, 0);
                accU[mi][ni] = __builtin_amdgcn_mfma_f32_16x16x32_bf16(a[mi], bu[ni], accU[mi][ni], 0, 0, 0);
            }
        __syncthreads();
    }

    // epilogue: h = silu(g)*u, C layout col=lane&15, row=(lane>>4)*4+r
    const int colb  = lane & 15;
    const int rquad = (lane >> 4) * 4;
    #pragma unroll
    for (int mi = 0; mi < 4; ++mi)
        #pragma unroll
        for (int ni = 0; ni < 2; ++ni) {
            int n = n0 + wn * 32 + ni * 16 + colb;
            #pragma unroll
            for (int r = 0; r < 4; ++r) {
                int ml = wm * 64 + mi * 16 + rquad + r;
                if (m0 + ml < cnt) {
                    float g = accG[mi][ni][r];
                    float u = accU[mi][ni][r];
                    float h = (g / (1.0f + __expf(-g))) * u;
                    hg[(size_t)(off + m0 + ml) * IDIM + n] = f2bf(h);
                }
            }
        }
}

// GEMM2: hg [cnt x 2048] bf16 @ down^T -> out rows scattered via perm (fp32)
__launch_bounds__(256, 2)
__global__ void k_gemm2(const unsigned short* __restrict__ hg,
                        const float* __restrict__ down_w,
                        float* __restrict__ out,
                        const int* __restrict__ ws_i,
                        const int* __restrict__ perm) {
    const int e   = blockIdx.z;
    const int cnt = ws_i[e];
    const int m0  = blockIdx.y * 128;
    if (m0 >= cnt) return;
    const int off = ws_i[16 + e];
    const int n0  = blockIdx.x * 64;

    const int tid  = threadIdx.x;
    const int lane = tid & 63;
    const int wave = tid >> 6;
    const int wm   = wave & 1;
    const int wn   = wave >> 1;

    __shared__ __align__(16) unsigned short lsA[128 * 56];
    __shared__ __align__(16) unsigned short lsB[64 * 56];

    const float* down_e = down_w + (size_t)e * DDIM * IDIM;

    ffrag acc[4][2];
    const ffrag fz = {0.f, 0.f, 0.f, 0.f};
    for (int mi = 0; mi < 4; ++mi)
        for (int ni = 0; ni < 2; ++ni) acc[mi][ni] = fz;

    for (int kt = 0; kt < IDIM / 32; ++kt) {
        const int k0 = kt * 32;
        #pragma unroll
        for (int i = 0; i < 2; ++i) {
            int c = tid + i * 256;
            int row = c >> 2, q = c & 3;
            int grow = off + m0 + row; if (grow > T_TOK - 1) grow = T_TOK - 1;
            const uint4 v = *reinterpret_cast<const uint4*>(hg + (size_t)grow * IDIM + k0 + q * 8);
            *reinterpret_cast<uint4*>(&lsA[row * 56 + q * 8]) = v;
        }
        #pragma unroll
        for (int i = 0; i < 2; ++i) {
            int c = tid + i * 256;           // 512 float4
            int row = c >> 3, q = c & 7;
            const float4 v = *reinterpret_cast<const float4*>(down_e + (size_t)(n0 + row) * IDIM + k0 + q * 4);
            uint2 o;
            o.x = f2bf(v.x) | ((unsigned)f2bf(v.y) << 16);
            o.y = f2bf(v.z) | ((unsigned)f2bf(v.w) << 16);
            *reinterpret_cast<uint2*>(&lsB[row * 56 + q * 4]) = o;
        }
        __syncthreads();

        const int koff = (lane >> 4) * 8;
        const int rsel = lane & 15;
        bfrag a[4], b[2];
        #pragma unroll
        for (int mi = 0; mi < 4; ++mi)
            a[mi] = *reinterpret_cast<const bfrag*>(&lsA[(wm * 64 + mi * 16 + rsel) * 56 + koff]);
        #pragma unroll
        for (int ni = 0; ni < 2; ++ni)
            b[ni] = *reinterpret_cast<const bfrag*>(&lsB[(wn * 32 + ni * 16 + rsel) * 56 + koff]);
        #pragma unroll
        for (int mi = 0; mi < 4; ++mi)
            #pragma unroll
            for (int ni = 0; ni < 2; ++ni)
                acc[mi][ni] = __builtin_amdgcn_mfma_f32_16x16x32_bf16(a[mi], b[ni], acc[mi][ni], 0, 0, 0);
        __syncthreads();
    }

    const int colb  = lane & 15;
    const int rquad = (lane >> 4) * 4;
    #pragma unroll
    for (int mi = 0; mi < 4; ++mi)
        #pragma unroll
        for (int ni = 0; ni < 2; ++ni) {
            int n = n0 + wn * 32 + ni * 16 + colb;
            #pragma unroll
            for (int r = 0; r < 4; ++r) {
                int ml = wm * 64 + mi * 16 + rquad + r;
                if (m0 + ml < cnt) {
                    int tok = perm[off + m0 + ml];
                    out[(size_t)tok * DDIM + n] = acc[mi][ni][r];
                }
            }
        }
}

extern "C" void kernel_launch(void* const* d_in, const int* in_sizes, int n_in,
                              void* d_out, int out_size, void* d_ws, size_t ws_size,
                              hipStream_t stream) {
    const float* x      = (const float*)d_in[0];
    const int*   pos    = (const int*)d_in[1];
    // d_in[2] behavior_index unused
    const float* gate_w = (const float*)d_in[3];
    const float* up_w   = (const float*)d_in[4];
    const float* down_w = (const float*)d_in[5];
    float* out = (float*)d_out;

    char* ws = (char*)d_ws;
    int* ws_i = (int*)ws;                                    // counts/cursors/offsets
    int* perm = (int*)(ws + 1024);                           // 16 KB
    unsigned short* xg = (unsigned short*)(ws + 32768);      // 6.3 MB (bf16 gathered x)
    unsigned short* hg = (unsigned short*)(ws + (8u << 20)); // 16.8 MB (bf16 h)

    hipMemsetAsync(ws, 0, 256, stream);
    k_hist<<<dim3(T_TOK / 256), dim3(256), 0, stream>>>(pos, ws_i);
    k_scan<<<dim3(1), dim3(64), 0, stream>>>(ws_i);
    k_perm<<<dim3(T_TOK / 256), dim3(256), 0, stream>>>(pos, ws_i, perm);
    k_gather<<<dim3(T_TOK), dim3(192), 0, stream>>>(x, perm, xg);

    dim3 g1(IDIM / 64, 32, NEXP);
    k_gemm1<<<g1, dim3(256), 0, stream>>>(xg, gate_w, up_w, hg, ws_i);
    dim3 g2(DDIM / 64, 32, NEXP);
    k_gemm2<<<g2, dim3(256), 0, stream>>>(hg, down_w, out, ws_i, perm);
}

// Round 3
// 305.351 us; speedup vs baseline: 1.1585x; 1.1585x over previous
//
#include <hip/hip_runtime.h>
#include <hip/hip_bf16.h>

#define T_TOK 4096
#define DDIM  768
#define IDIM  2048
#define NEXP  8

typedef __attribute__((ext_vector_type(8))) short  bfrag;   // 8 bf16 = 4 VGPR
typedef __attribute__((ext_vector_type(4))) float  ffrag;   // 4 f32 acc

static __device__ __forceinline__ unsigned short f2bf(float f) {
    union { float f; unsigned u; } v; v.f = f;
    unsigned r = v.u + 0x7FFFu + ((v.u >> 16) & 1u);   // RNE
    return (unsigned short)(r >> 16);
}

static __device__ __forceinline__ unsigned cvt2(float x, float y) {
    return (unsigned)f2bf(x) | ((unsigned)f2bf(y) << 16);
}

// ws int layout: counts[8] @0, offsets[9] @16
// fused histogram + scan + rank/permute, single block (LDS atomics)
__global__ void k_sort(const int* __restrict__ pos, int* __restrict__ ws_i,
                       int* __restrict__ perm) {
    __shared__ int hist[NEXP], cursor[NEXP];
    const int tid = threadIdx.x;
    if (tid < NEXP) hist[tid] = 0;
    __syncthreads();
    for (int i = tid; i < T_TOK; i += 1024)
        atomicAdd(&hist[pos[i]], 1);
    __syncthreads();
    if (tid == 0) {
        int s = 0;
        for (int e = 0; e < NEXP; ++e) {
            cursor[e] = s;
            ws_i[e] = hist[e];
            ws_i[16 + e] = s;
            s += hist[e];
        }
        ws_i[16 + NEXP] = s;
    }
    __syncthreads();
    for (int i = tid; i < T_TOK; i += 1024) {
        int p = atomicAdd(&cursor[pos[i]], 1);
        perm[p] = i;
    }
}

// gather + fp32->bf16: one block per gathered row
__global__ void k_gather(const float* __restrict__ x, const int* __restrict__ perm,
                         unsigned short* __restrict__ xg) {
    int p = blockIdx.x;
    int tok = perm[p];
    int j = threadIdx.x * 4;
    const float4 v = *reinterpret_cast<const float4*>(x + (size_t)tok * DDIM + j);
    uint2 o;
    o.x = cvt2(v.x, v.y);
    o.y = cvt2(v.z, v.w);
    *reinterpret_cast<uint2*>(xg + (size_t)p * DDIM + j) = o;
}

// GEMM1: xg[cnt x 768] bf16 @ gate/up^T -> h = silu(g)*u, bf16
// BM=128, BN=64 (each matrix), BK=32; register-prefetch pipeline
__launch_bounds__(256, 2)
__global__ void k_gemm1(const unsigned short* __restrict__ xg,
                        const float* __restrict__ gate_w,
                        const float* __restrict__ up_w,
                        unsigned short* __restrict__ hg,
                        const int* __restrict__ ws_i) {
    const int e   = blockIdx.z;
    const int cnt = ws_i[e];
    const int m0  = blockIdx.y * 128;
    if (m0 >= cnt) return;
    const int off = ws_i[16 + e];
    const int n0  = blockIdx.x * 64;

    const int tid  = threadIdx.x;
    const int lane = tid & 63;
    const int wave = tid >> 6;
    const int wm   = wave & 1;
    const int wn   = wave >> 1;

    // row stride 56 bf16 = 112 B: 16B-aligned, bank-rotating (conflict-light)
    __shared__ __align__(16) unsigned short lsA[128 * 56];
    __shared__ __align__(16) unsigned short lsG[64 * 56];
    __shared__ __align__(16) unsigned short lsU[64 * 56];

    const float* gate_e = gate_w + (size_t)e * (IDIM * DDIM);
    const float* up_e   = up_w   + (size_t)e * (IDIM * DDIM);

    // staging maps
    const int ar = tid >> 2;      // A rows 0..63 (+64 for second chunk)
    const int aq = tid & 3;       // 16B chunk within 32-elem row
    const int br = tid >> 3;      // B rows 0..31 (+32)
    const int bq = tid & 7;       // float4 within 32-elem row

    int g0 = off + m0 + ar;      if (g0 > T_TOK - 1) g0 = T_TOK - 1;
    int g1 = off + m0 + ar + 64; if (g1 > T_TOK - 1) g1 = T_TOK - 1;
    const unsigned short* a0p = xg + (size_t)g0 * DDIM + aq * 8;
    const unsigned short* a1p = xg + (size_t)g1 * DDIM + aq * 8;
    const float* gp0 = gate_e + (size_t)(n0 + br)      * DDIM + bq * 4;
    const float* gp1 = gate_e + (size_t)(n0 + br + 32) * DDIM + bq * 4;
    const float* up0 = up_e   + (size_t)(n0 + br)      * DDIM + bq * 4;
    const float* up1 = up_e   + (size_t)(n0 + br + 32) * DDIM + bq * 4;

    // prologue loads (kt = 0)
    uint4  pa0 = *reinterpret_cast<const uint4*>(a0p);
    uint4  pa1 = *reinterpret_cast<const uint4*>(a1p);
    float4 pg0 = *reinterpret_cast<const float4*>(gp0);
    float4 pg1 = *reinterpret_cast<const float4*>(gp1);
    float4 pu0 = *reinterpret_cast<const float4*>(up0);
    float4 pu1 = *reinterpret_cast<const float4*>(up1);

    ffrag accG[4][2], accU[4][2];
    const ffrag fz = {0.f, 0.f, 0.f, 0.f};
    for (int mi = 0; mi < 4; ++mi)
        for (int ni = 0; ni < 2; ++ni) { accG[mi][ni] = fz; accU[mi][ni] = fz; }

    const int koff = (lane >> 4) * 8;
    const int rsel = lane & 15;

    for (int kt = 0; kt < DDIM / 32; ++kt) {
        // LDS write of prefetched tile (compiler inserts vmcnt wait)
        *reinterpret_cast<uint4*>(&lsA[ar * 56 + aq * 8])        = pa0;
        *reinterpret_cast<uint4*>(&lsA[(ar + 64) * 56 + aq * 8]) = pa1;
        { uint2 o; o.x = cvt2(pg0.x, pg0.y); o.y = cvt2(pg0.z, pg0.w);
          *reinterpret_cast<uint2*>(&lsG[br * 56 + bq * 4]) = o; }
        { uint2 o; o.x = cvt2(pg1.x, pg1.y); o.y = cvt2(pg1.z, pg1.w);
          *reinterpret_cast<uint2*>(&lsG[(br + 32) * 56 + bq * 4]) = o; }
        { uint2 o; o.x = cvt2(pu0.x, pu0.y); o.y = cvt2(pu0.z, pu0.w);
          *reinterpret_cast<uint2*>(&lsU[br * 56 + bq * 4]) = o; }
        { uint2 o; o.x = cvt2(pu1.x, pu1.y); o.y = cvt2(pu1.z, pu1.w);
          *reinterpret_cast<uint2*>(&lsU[(br + 32) * 56 + bq * 4]) = o; }
        __syncthreads();

        // issue next tile's global loads; they fly during ds_read + MFMA
        if (kt < DDIM / 32 - 1) {
            const int kb = (kt + 1) * 32;
            pa0 = *reinterpret_cast<const uint4*>(a0p + kb);
            pa1 = *reinterpret_cast<const uint4*>(a1p + kb);
            pg0 = *reinterpret_cast<const float4*>(gp0 + kb);
            pg1 = *reinterpret_cast<const float4*>(gp1 + kb);
            pu0 = *reinterpret_cast<const float4*>(up0 + kb);
            pu1 = *reinterpret_cast<const float4*>(up1 + kb);
        }

        bfrag a[4], bg[2], bu[2];
        #pragma unroll
        for (int mi = 0; mi < 4; ++mi)
            a[mi] = *reinterpret_cast<const bfrag*>(&lsA[(wm * 64 + mi * 16 + rsel) * 56 + koff]);
        #pragma unroll
        for (int ni = 0; ni < 2; ++ni) {
            bg[ni] = *reinterpret_cast<const bfrag*>(&lsG[(wn * 32 + ni * 16 + rsel) * 56 + koff]);
            bu[ni] = *reinterpret_cast<const bfrag*>(&lsU[(wn * 32 + ni * 16 + rsel) * 56 + koff]);
        }
        #pragma unroll
        for (int mi = 0; mi < 4; ++mi)
            #pragma unroll
            for (int ni = 0; ni < 2; ++ni) {
                accG[mi][ni] = __builtin_amdgcn_mfma_f32_16x16x32_bf16(a[mi], bg[ni], accG[mi][ni], 0, 0, 0);
                accU[mi][ni] = __builtin_amdgcn_mfma_f32_16x16x32_bf16(a[mi], bu[ni], accU[mi][ni], 0, 0, 0);
            }
        __syncthreads();
    }

    // epilogue: h = silu(g)*u; C layout col=lane&15, row=(lane>>4)*4+r
    const int colb  = lane & 15;
    const int rquad = (lane >> 4) * 4;
    #pragma unroll
    for (int mi = 0; mi < 4; ++mi)
        #pragma unroll
        for (int ni = 0; ni < 2; ++ni) {
            int n = n0 + wn * 32 + ni * 16 + colb;
            #pragma unroll
            for (int r = 0; r < 4; ++r) {
                int ml = wm * 64 + mi * 16 + rquad + r;
                if (m0 + ml < cnt) {
                    float g = accG[mi][ni][r];
                    float u = accU[mi][ni][r];
                    float h = (g / (1.0f + __expf(-g))) * u;
                    hg[(size_t)(off + m0 + ml) * IDIM + n] = f2bf(h);
                }
            }
        }
}

// GEMM2: hg[cnt x 2048] bf16 @ down^T, split-K=4, atomicAdd scatter to out (fp32)
__launch_bounds__(256, 2)
__global__ void k_gemm2(const unsigned short* __restrict__ hg,
                        const float* __restrict__ down_w,
                        float* __restrict__ out,
                        const int* __restrict__ ws_i,
                        const int* __restrict__ perm) {
    const int e     = blockIdx.z & 7;
    const int split = blockIdx.z >> 3;       // 0..3, K-chunk of 512
    const int cnt = ws_i[e];
    const int m0  = blockIdx.y * 128;
    if (m0 >= cnt) return;
    const int off = ws_i[16 + e];
    const int n0  = blockIdx.x * 64;

    const int tid  = threadIdx.x;
    const int lane = tid & 63;
    const int wave = tid >> 6;
    const int wm   = wave & 1;
    const int wn   = wave >> 1;

    __shared__ __align__(16) unsigned short lsA[128 * 56];
    __shared__ __align__(16) unsigned short lsB[64 * 56];

    const float* down_e = down_w + (size_t)e * (DDIM * IDIM);

    const int ar = tid >> 2;
    const int aq = tid & 3;
    const int br = tid >> 3;
    const int bq = tid & 7;

    int g0 = off + m0 + ar;      if (g0 > T_TOK - 1) g0 = T_TOK - 1;
    int g1 = off + m0 + ar + 64; if (g1 > T_TOK - 1) g1 = T_TOK - 1;
    const unsigned short* a0p = hg + (size_t)g0 * IDIM + split * 512 + aq * 8;
    const unsigned short* a1p = hg + (size_t)g1 * IDIM + split * 512 + aq * 8;
    const float* bp0 = down_e + (size_t)(n0 + br)      * IDIM + split * 512 + bq * 4;
    const float* bp1 = down_e + (size_t)(n0 + br + 32) * IDIM + split * 512 + bq * 4;

    uint4  pa0 = *reinterpret_cast<const uint4*>(a0p);
    uint4  pa1 = *reinterpret_cast<const uint4*>(a1p);
    float4 pb0 = *reinterpret_cast<const float4*>(bp0);
    float4 pb1 = *reinterpret_cast<const float4*>(bp1);

    ffrag acc[4][2];
    const ffrag fz = {0.f, 0.f, 0.f, 0.f};
    for (int mi = 0; mi < 4; ++mi)
        for (int ni = 0; ni < 2; ++ni) acc[mi][ni] = fz;

    const int koff = (lane >> 4) * 8;
    const int rsel = lane & 15;

    for (int kt = 0; kt < 16; ++kt) {
        *reinterpret_cast<uint4*>(&lsA[ar * 56 + aq * 8])        = pa0;
        *reinterpret_cast<uint4*>(&lsA[(ar + 64) * 56 + aq * 8]) = pa1;
        { uint2 o; o.x = cvt2(pb0.x, pb0.y); o.y = cvt2(pb0.z, pb0.w);
          *reinterpret_cast<uint2*>(&lsB[br * 56 + bq * 4]) = o; }
        { uint2 o; o.x = cvt2(pb1.x, pb1.y); o.y = cvt2(pb1.z, pb1.w);
          *reinterpret_cast<uint2*>(&lsB[(br + 32) * 56 + bq * 4]) = o; }
        __syncthreads();

        if (kt < 15) {
            const int kb = (kt + 1) * 32;
            pa0 = *reinterpret_cast<const uint4*>(a0p + kb);
            pa1 = *reinterpret_cast<const uint4*>(a1p + kb);
            pb0 = *reinterpret_cast<const float4*>(bp0 + kb);
            pb1 = *reinterpret_cast<const float4*>(bp1 + kb);
        }

        bfrag a[4], b[2];
        #pragma unroll
        for (int mi = 0; mi < 4; ++mi)
            a[mi] = *reinterpret_cast<const bfrag*>(&lsA[(wm * 64 + mi * 16 + rsel) * 56 + koff]);
        #pragma unroll
        for (int ni = 0; ni < 2; ++ni)
            b[ni] = *reinterpret_cast<const bfrag*>(&lsB[(wn * 32 + ni * 16 + rsel) * 56 + koff]);
        #pragma unroll
        for (int mi = 0; mi < 4; ++mi)
            #pragma unroll
            for (int ni = 0; ni < 2; ++ni)
                acc[mi][ni] = __builtin_amdgcn_mfma_f32_16x16x32_bf16(a[mi], b[ni], acc[mi][ni], 0, 0, 0);
        __syncthreads();
    }

    const int colb  = lane & 15;
    const int rquad = (lane >> 4) * 4;
    #pragma unroll
    for (int mi = 0; mi < 4; ++mi)
        #pragma unroll
        for (int ni = 0; ni < 2; ++ni) {
            int n = n0 + wn * 32 + ni * 16 + colb;
            #pragma unroll
            for (int r = 0; r < 4; ++r) {
                int ml = wm * 64 + mi * 16 + rquad + r;
                if (m0 + ml < cnt) {
                    int tok = perm[off + m0 + ml];
                    unsafeAtomicAdd(&out[(size_t)tok * DDIM + n], acc[mi][ni][r]);
                }
            }
        }
}

extern "C" void kernel_launch(void* const* d_in, const int* in_sizes, int n_in,
                              void* d_out, int out_size, void* d_ws, size_t ws_size,
                              hipStream_t stream) {
    const float* x      = (const float*)d_in[0];
    const int*   pos    = (const int*)d_in[1];
    const float* gate_w = (const float*)d_in[3];
    const float* up_w   = (const float*)d_in[4];
    const float* down_w = (const float*)d_in[5];
    float* out = (float*)d_out;

    char* ws = (char*)d_ws;
    int* ws_i = (int*)ws;
    int* perm = (int*)(ws + 1024);
    unsigned short* xg = (unsigned short*)(ws + 32768);      // 6.3 MB bf16
    unsigned short* hg = (unsigned short*)(ws + (8u << 20)); // 16.8 MB bf16

    (void)hipMemsetAsync(d_out, 0, (size_t)out_size * sizeof(float), stream);
    k_sort<<<dim3(1), dim3(1024), 0, stream>>>(pos, ws_i, perm);
    k_gather<<<dim3(T_TOK), dim3(192), 0, stream>>>(x, perm, xg);

    dim3 g1(IDIM / 64, 32, NEXP);
    k_gemm1<<<g1, dim3(256), 0, stream>>>(xg, gate_w, up_w, hg, ws_i);
    dim3 g2(DDIM / 64, 32, NEXP * 4);   // z = expert | split<<3
    k_gemm2<<<g2, dim3(256), 0, stream>>>(hg, down_w, out, ws_i, perm);
}